// Round 1
// baseline (1384.221 us; speedup 1.0000x reference)
//
#include <hip/hip_runtime.h>
#include <cstdint>
#include <cstddef>

#define N_NODES 100000
#define D 64
#define NNZ 3200000
#define BB 64
#define LL 200
#define NP 391          // ceil(N_NODES/256)
#define BM_WORDS 3200   // >= ceil(N_NODES/32)=3125, padded

// ---------------------------------------------------------------- utilities
__device__ __forceinline__ float wave_sum(float x) {
#pragma unroll
  for (int o = 32; o; o >>= 1) x += __shfl_xor(x, o, 64);
  return x;
}

// ---------------------------------------------------------------- mark rows needed by output
__global__ void mark_kernel(const int* __restrict__ input, uint32_t* __restrict__ bm) {
  int t = blockIdx.x * 256 + threadIdx.x;
  if (t < BB * LL) {
    int i = input[t];
    atomicOr(&bm[i >> 5], 1u << (i & 31));
  }
}

// ---------------------------------------------------------------- gate: e2 = u*sigmoid(u@w0+b0), e3 likewise
__global__ __launch_bounds__(256) void gate_kernel(
    const float* __restrict__ u, const float* __restrict__ w0,
    const float* __restrict__ w1, const float* __restrict__ b0,
    const float* __restrict__ b1, float* __restrict__ e2, float* __restrict__ e3) {
  __shared__ float sw0[D * D];
  __shared__ float sw1[D * D];
  __shared__ float sb0[D], sb1[D];
  for (int t = threadIdx.x; t < D * D; t += 256) { sw0[t] = w0[t]; sw1[t] = w1[t]; }
  if (threadIdx.x < D) { sb0[threadIdx.x] = b0[threadIdx.x]; sb1[threadIdx.x] = b1[threadIdx.x]; }
  __syncthreads();
  int wave = (blockIdx.x * 256 + threadIdx.x) >> 6;
  int lane = threadIdx.x & 63;
  int nw = (gridDim.x * 256) >> 6;
  for (int i = wave; i < N_NODES; i += nw) {
    float uv = u[i * D + lane];
    float a0 = 0.f, a1 = 0.f;
#pragma unroll
    for (int k = 0; k < D; ++k) {
      float uk = __shfl(uv, k, 64);
      a0 = fmaf(uk, sw0[k * D + lane], a0);
      a1 = fmaf(uk, sw1[k * D + lane], a1);
    }
    a0 += sb0[lane];
    a1 += sb1[lane];
    float s0 = 1.f / (1.f + expf(-a0));
    float s1 = 1.f / (1.f + expf(-a1));
    e2[i * D + lane] = uv * s0;
    e3[i * D + lane] = uv * s1;
  }
}

// ---------------------------------------------------------------- counting sort: hist / scan / scatter
__global__ void hist_kernel(const int* __restrict__ dsts, uint32_t* __restrict__ counts) {
  int stride = gridDim.x * blockDim.x;
  for (int e = blockIdx.x * blockDim.x + threadIdx.x; e < NNZ; e += stride)
    atomicAdd(&counts[dsts[e]], 1u);
}

__global__ void scan_phase1(const uint32_t* __restrict__ counts, uint32_t* __restrict__ partial) {
  __shared__ uint32_t s[256];
  int i = blockIdx.x * 256 + threadIdx.x;
  uint32_t v = (i < N_NODES) ? counts[i] : 0u;
  s[threadIdx.x] = v;
  __syncthreads();
  for (int o = 128; o; o >>= 1) {
    if (threadIdx.x < o) s[threadIdx.x] += s[threadIdx.x + o];
    __syncthreads();
  }
  if (threadIdx.x == 0) partial[blockIdx.x] = s[0];
}

__global__ void scan_phase2(uint32_t* __restrict__ partial, int np) {
  __shared__ uint32_t s[256];
  __shared__ uint32_t carry;
  if (threadIdx.x == 0) carry = 0u;
  __syncthreads();
  for (int start = 0; start < np; start += 256) {
    int i = start + threadIdx.x;
    uint32_t v = (i < np) ? partial[i] : 0u;
    s[threadIdx.x] = v;
    __syncthreads();
    for (int o = 1; o < 256; o <<= 1) {
      uint32_t t = (threadIdx.x >= o) ? s[threadIdx.x - o] : 0u;
      __syncthreads();
      s[threadIdx.x] += t;
      __syncthreads();
    }
    uint32_t incl = s[threadIdx.x];
    uint32_t excl = incl - v + carry;
    if (i < np) partial[i] = excl;
    __syncthreads();
    if (threadIdx.x == 255) carry += incl;
    __syncthreads();
  }
}

__global__ void scan_phase3(const uint32_t* __restrict__ counts, const uint32_t* __restrict__ partial,
                            uint32_t* __restrict__ row_start, uint32_t* __restrict__ cursor) {
  __shared__ uint32_t s[256];
  int i = blockIdx.x * 256 + threadIdx.x;
  uint32_t v = (i < N_NODES) ? counts[i] : 0u;
  s[threadIdx.x] = v;
  __syncthreads();
  for (int o = 1; o < 256; o <<= 1) {
    uint32_t t = (threadIdx.x >= o) ? s[threadIdx.x - o] : 0u;
    __syncthreads();
    s[threadIdx.x] += t;
    __syncthreads();
  }
  uint32_t excl = s[threadIdx.x] - v + partial[blockIdx.x];
  if (i < N_NODES) {
    row_start[i] = excl;
    cursor[i] = excl;
  }
}

__global__ void scatter_kernel(const int* __restrict__ dsts, const int* __restrict__ srcs,
                               const float* __restrict__ val, uint32_t* __restrict__ cursor,
                               uint2* __restrict__ pairs) {
  int stride = gridDim.x * blockDim.x;
  for (int e = blockIdx.x * blockDim.x + threadIdx.x; e < NNZ; e += stride) {
    int d = dsts[e];
    uint32_t pos = atomicAdd(&cursor[d], 1u);
    pairs[pos] = make_uint2((uint32_t)srcs[e], __float_as_uint(val[e]));
  }
}

// ---------------------------------------------------------------- CSR spmm: wave per destination row, no atomics
template <bool FILTER>
__global__ __launch_bounds__(256) void csr_reduce_kernel(
    const uint32_t* __restrict__ row_start, const uint32_t* __restrict__ counts,
    const uint2* __restrict__ pairs, const float* __restrict__ xin,
    float* __restrict__ xout, const uint32_t* __restrict__ bitmap) {
  int wave = (blockIdx.x * 256 + threadIdx.x) >> 6;
  int lane = threadIdx.x & 63;
  int nw = (gridDim.x * 256) >> 6;
  for (int i = wave; i < N_NODES; i += nw) {
    if (FILTER) {
      if (!((bitmap[i >> 5] >> (i & 31)) & 1u)) continue;
    }
    uint32_t cnt = counts[i];
    uint32_t base = row_start[i];
    float acc = 0.f;
    for (uint32_t j0 = 0; j0 < cnt; j0 += 64) {
      int nb = (int)min(64u, cnt - j0);
      uint2 p = make_uint2(0u, 0u);
      if ((int)j0 + lane < (int)cnt) p = pairs[base + j0 + lane];
      for (int jj = 0; jj < nb; ++jj) {
        int src = __shfl((int)p.x, jj, 64);
        float v = __uint_as_float((uint32_t)__shfl((int)p.y, jj, 64));
        acc = fmaf(v, xin[(size_t)src * D + lane], acc);
      }
    }
    xout[(size_t)i * D + lane] = acc;
  }
}

// ---------------------------------------------------------------- final: fused acc/l2norm/mix + seq attention
__global__ __launch_bounds__(256) void final_kernel(
    const int* __restrict__ input,
    const float* __restrict__ e20, const float* __restrict__ e21, const float* __restrict__ e22,
    const float* __restrict__ e30, const float* __restrict__ e31, const float* __restrict__ e32,
    const float* __restrict__ att, const float* __restrict__ att_m,
    float* __restrict__ out_Lcas, float* __restrict__ out_cas) {
  __shared__ float cas[LL * D];  // 51.2 KB
  __shared__ float sv[D];
  __shared__ float sscore[LL];
  __shared__ float red[8];
  int b = blockIdx.x, tid = threadIdx.x;
  // v = att_m @ att^T
  if (tid < D) {
    float a = 0.f;
#pragma unroll
    for (int j = 0; j < D; ++j) a = fmaf(att_m[tid * D + j], att[j], a);
    sv[tid] = a;
  }
  __syncthreads();
  int wv = tid >> 6, lane = tid & 63;
  float svl = sv[lane];
  for (int l = wv; l < LL; l += 4) {
    int i = input[b * LL + l];
    size_t o = (size_t)i * D + lane;
    float v20 = e20[o], v21 = e21[o], v22 = e22[o];
    float v30 = e30[o], v31 = e31[o], v32 = e32[o];
    float n21 = fmaxf(sqrtf(wave_sum(v21 * v21)), 1e-12f);
    float n22 = fmaxf(sqrtf(wave_sum(v22 * v22)), 1e-12f);
    float n31 = fmaxf(sqrtf(wave_sum(v31 * v31)), 1e-12f);
    float n32 = fmaxf(sqrtf(wave_sum(v32 * v32)), 1e-12f);
    float a2 = v20 + v21 / n21 + v22 / n22;
    float a3 = v30 + v31 / n31 + v32 / n32;
    float w2 = wave_sum(a2 * svl);
    float w3 = wave_sum(a3 * svl);
    float mx = fmaxf(w2, w3);
    float ex2 = expf(w2 - mx), ex3 = expf(w3 - mx);
    float inv = 1.f / (ex2 + ex3);
    float mix = (ex2 * a2 + ex3 * a3) * inv;
    cas[l * D + lane] = mix;
    out_cas[(size_t)(b * LL + l) * D + lane] = mix;
  }
  __syncthreads();
  // scores vs row 0
  for (int l = wv; l < LL; l += 4) {
    float s = wave_sum(cas[lane] * cas[l * D + lane]) * 0.125f;  // 1/sqrt(64)
    int iv = input[b * LL + l];
    s = (iv == 0) ? -1e9f : s;
    if (lane == 0) sscore[l] = s;
  }
  __syncthreads();
  // softmax over L
  float m = -INFINITY;
  for (int l = tid; l < LL; l += 256) m = fmaxf(m, sscore[l]);
#pragma unroll
  for (int o = 32; o; o >>= 1) m = fmaxf(m, __shfl_xor(m, o, 64));
  if (lane == 0) red[wv] = m;
  __syncthreads();
  m = fmaxf(fmaxf(red[0], red[1]), fmaxf(red[2], red[3]));
  float sum = 0.f;
  for (int l = tid; l < LL; l += 256) sum += expf(sscore[l] - m);
  sum = wave_sum(sum);
  if (lane == 0) red[4 + wv] = sum;
  __syncthreads();
  float inv = 1.f / (red[4] + red[5] + red[6] + red[7]);
  for (int l = tid; l < LL; l += 256) sscore[l] = expf(sscore[l] - m) * inv;
  __syncthreads();
  for (int t = tid; t < LL * D; t += 256)
    out_Lcas[(size_t)b * LL * D + t] = sscore[t >> 6] * cas[t];
}

// ---------------------------------------------------------------- launch
extern "C" void kernel_launch(void* const* d_in, const int* in_sizes, int n_in,
                              void* d_out, int out_size, void* d_ws, size_t ws_size,
                              hipStream_t stream) {
  const int* input = (const int*)d_in[0];
  const int* h_item_idx = (const int*)d_in[1];
  const float* h_item_val = (const float*)d_in[2];
  const int* h_user_idx = (const int*)d_in[3];
  const float* h_user_val = (const float*)d_in[4];
  const float* user_emb = (const float*)d_in[5];
  const float* w0 = (const float*)d_in[6];
  const float* w1 = (const float*)d_in[7];
  const float* b0 = (const float*)d_in[8];
  const float* b1 = (const float*)d_in[9];
  const float* att = (const float*)d_in[10];
  const float* att_m = (const float*)d_in[11];

  float* out = (float*)d_out;
  float* out_Lcas = out;                       // B*L*D
  float* out_cas = out + (size_t)BB * LL * D;  // B*L*D

  const size_t ND = (size_t)N_NODES * D;  // 6.4M floats
  char* ws = (char*)d_ws;
  float* e20 = (float*)ws; ws += ND * 4;
  float* e30 = (float*)ws; ws += ND * 4;
  float* e21 = (float*)ws; ws += ND * 4;
  float* e31 = (float*)ws; ws += ND * 4;
  float* e22 = (float*)ws; ws += ND * 4;
  float* e32 = (float*)ws; ws += ND * 4;
  uint2* pairs = (uint2*)ws; ws += (size_t)NNZ * 8;
  uint32_t* counts = (uint32_t*)ws; ws += (size_t)N_NODES * 4;
  uint32_t* row_start = (uint32_t*)ws; ws += (size_t)N_NODES * 4;
  uint32_t* cursor = (uint32_t*)ws; ws += (size_t)N_NODES * 4;
  uint32_t* bitmap = (uint32_t*)ws; ws += (size_t)BM_WORDS * 4;
  uint32_t* partial = (uint32_t*)ws; ws += 512 * 4;

  const int* item_dst = h_item_idx;
  const int* item_src = h_item_idx + NNZ;
  const int* user_dst = h_user_idx;
  const int* user_src = h_user_idx + NNZ;

  // bitmap of rows actually needed by the output gather
  hipMemsetAsync(bitmap, 0, (size_t)BM_WORDS * 4, stream);
  mark_kernel<<<(BB * LL + 255) / 256, 256, 0, stream>>>(input, bitmap);

  // gate
  gate_kernel<<<2048, 256, 0, stream>>>(user_emb, w0, w1, b0, b1, e20, e30);

  // ---- item graph: sort once, reduce layer1 (full) + layer2 (filtered)
  hipMemsetAsync(counts, 0, (size_t)N_NODES * 4, stream);
  hist_kernel<<<1024, 256, 0, stream>>>(item_dst, counts);
  scan_phase1<<<NP, 256, 0, stream>>>(counts, partial);
  scan_phase2<<<1, 256, 0, stream>>>(partial, NP);
  scan_phase3<<<NP, 256, 0, stream>>>(counts, partial, row_start, cursor);
  scatter_kernel<<<1024, 256, 0, stream>>>(item_dst, item_src, h_item_val, cursor, pairs);
  csr_reduce_kernel<false><<<4096, 256, 0, stream>>>(row_start, counts, pairs, e20, e21, nullptr);
  csr_reduce_kernel<true><<<4096, 256, 0, stream>>>(row_start, counts, pairs, e21, e22, bitmap);

  // ---- user graph
  hipMemsetAsync(counts, 0, (size_t)N_NODES * 4, stream);
  hist_kernel<<<1024, 256, 0, stream>>>(user_dst, counts);
  scan_phase1<<<NP, 256, 0, stream>>>(counts, partial);
  scan_phase2<<<1, 256, 0, stream>>>(partial, NP);
  scan_phase3<<<NP, 256, 0, stream>>>(counts, partial, row_start, cursor);
  scatter_kernel<<<1024, 256, 0, stream>>>(user_dst, user_src, h_user_val, cursor, pairs);
  csr_reduce_kernel<false><<<4096, 256, 0, stream>>>(row_start, counts, pairs, e30, e31, nullptr);
  csr_reduce_kernel<true><<<4096, 256, 0, stream>>>(row_start, counts, pairs, e31, e32, bitmap);

  // ---- fused acc / l2norm / attention-mix / sequence attention
  final_kernel<<<BB, 256, 0, stream>>>(input, e20, e21, e22, e30, e31, e32,
                                       att, att_m, out_Lcas, out_cas);
}

// Round 2
// 1174.172 us; speedup vs baseline: 1.1789x; 1.1789x over previous
//
#include <hip/hip_runtime.h>
#include <cstdint>
#include <cstddef>

#define N_NODES 100000
#define D 64
#define NNZ 3200000
#define BB 64
#define LL 200
#define NP 391          // ceil(N_NODES/256)
#define BM_WORDS 3200   // >= ceil(N_NODES/32)=3125, padded

// ---------------------------------------------------------------- utilities
__device__ __forceinline__ float wave_sum(float x) {
#pragma unroll
  for (int o = 32; o; o >>= 1) x += __shfl_xor(x, o, 64);
  return x;
}

// ---------------------------------------------------------------- mark rows needed by output + build compact list
__global__ void mark_kernel(const int* __restrict__ input, uint32_t* __restrict__ bm,
                            int* __restrict__ list, int* __restrict__ nlist) {
  int t = blockIdx.x * 256 + threadIdx.x;
  if (t < BB * LL) {
    int i = input[t];
    uint32_t bit = 1u << (i & 31);
    uint32_t old = atomicOr(&bm[i >> 5], bit);
    if (!(old & bit)) {
      int p = atomicAdd(nlist, 1);
      list[p] = i;
    }
  }
}

// ---------------------------------------------------------------- gate: e2 = u*sigmoid(u@w0+b0), e3 likewise
__global__ __launch_bounds__(256) void gate_kernel(
    const float* __restrict__ u, const float* __restrict__ w0,
    const float* __restrict__ w1, const float* __restrict__ b0,
    const float* __restrict__ b1, float* __restrict__ e2, float* __restrict__ e3) {
  __shared__ float sw0[D * D];
  __shared__ float sw1[D * D];
  __shared__ float sb0[D], sb1[D];
  for (int t = threadIdx.x; t < D * D; t += 256) { sw0[t] = w0[t]; sw1[t] = w1[t]; }
  if (threadIdx.x < D) { sb0[threadIdx.x] = b0[threadIdx.x]; sb1[threadIdx.x] = b1[threadIdx.x]; }
  __syncthreads();
  int wave = (blockIdx.x * 256 + threadIdx.x) >> 6;
  int lane = threadIdx.x & 63;
  int nw = (gridDim.x * 256) >> 6;
  for (int i = wave; i < N_NODES; i += nw) {
    float uv = u[i * D + lane];
    float a0 = 0.f, a1 = 0.f;
#pragma unroll
    for (int k = 0; k < D; ++k) {
      float uk = __shfl(uv, k, 64);
      a0 = fmaf(uk, sw0[k * D + lane], a0);
      a1 = fmaf(uk, sw1[k * D + lane], a1);
    }
    a0 += sb0[lane];
    a1 += sb1[lane];
    float s0 = 1.f / (1.f + expf(-a0));
    float s1 = 1.f / (1.f + expf(-a1));
    e2[i * D + lane] = uv * s0;
    e3[i * D + lane] = uv * s1;
  }
}

// ---------------------------------------------------------------- counting sort: hist / scan / scatter
__global__ void hist_kernel(const int* __restrict__ dsts, uint32_t* __restrict__ counts) {
  int stride = gridDim.x * blockDim.x;
  for (int e = blockIdx.x * blockDim.x + threadIdx.x; e < NNZ; e += stride)
    atomicAdd(&counts[dsts[e]], 1u);
}

__global__ void scan_phase1(const uint32_t* __restrict__ counts, uint32_t* __restrict__ partial) {
  __shared__ uint32_t s[256];
  int i = blockIdx.x * 256 + threadIdx.x;
  uint32_t v = (i < N_NODES) ? counts[i] : 0u;
  s[threadIdx.x] = v;
  __syncthreads();
  for (int o = 128; o; o >>= 1) {
    if (threadIdx.x < o) s[threadIdx.x] += s[threadIdx.x + o];
    __syncthreads();
  }
  if (threadIdx.x == 0) partial[blockIdx.x] = s[0];
}

__global__ void scan_phase2(uint32_t* __restrict__ partial, int np) {
  __shared__ uint32_t s[256];
  __shared__ uint32_t carry;
  if (threadIdx.x == 0) carry = 0u;
  __syncthreads();
  for (int start = 0; start < np; start += 256) {
    int i = start + threadIdx.x;
    uint32_t v = (i < np) ? partial[i] : 0u;
    s[threadIdx.x] = v;
    __syncthreads();
    for (int o = 1; o < 256; o <<= 1) {
      uint32_t t = (threadIdx.x >= o) ? s[threadIdx.x - o] : 0u;
      __syncthreads();
      s[threadIdx.x] += t;
      __syncthreads();
    }
    uint32_t incl = s[threadIdx.x];
    uint32_t excl = incl - v + carry;
    if (i < np) partial[i] = excl;
    __syncthreads();
    if (threadIdx.x == 255) carry += incl;
    __syncthreads();
  }
}

__global__ void scan_phase3(const uint32_t* __restrict__ counts, const uint32_t* __restrict__ partial,
                            uint32_t* __restrict__ row_start, uint32_t* __restrict__ cursor) {
  __shared__ uint32_t s[256];
  int i = blockIdx.x * 256 + threadIdx.x;
  uint32_t v = (i < N_NODES) ? counts[i] : 0u;
  s[threadIdx.x] = v;
  __syncthreads();
  for (int o = 1; o < 256; o <<= 1) {
    uint32_t t = (threadIdx.x >= o) ? s[threadIdx.x - o] : 0u;
    __syncthreads();
    s[threadIdx.x] += t;
    __syncthreads();
  }
  uint32_t excl = s[threadIdx.x] - v + partial[blockIdx.x];
  if (i < N_NODES) {
    row_start[i] = excl;
    cursor[i] = excl;
  }
}

__global__ void scatter_kernel(const int* __restrict__ dsts, const int* __restrict__ srcs,
                               const float* __restrict__ val, uint32_t* __restrict__ cursor,
                               uint2* __restrict__ pairs) {
  int stride = gridDim.x * blockDim.x;
  for (int e = blockIdx.x * blockDim.x + threadIdx.x; e < NNZ; e += stride) {
    int d = dsts[e];
    uint32_t pos = atomicAdd(&cursor[d], 1u);
    pairs[pos] = make_uint2((uint32_t)srcs[e], __float_as_uint(val[e]));
  }
}

// ---------------------------------------------------------------- CSR spmm: wave per row, 4 edges/instr via float4
// lane = g*16 + c : group g in [0,4) handles edges e ≡ g (mod 4); c in [0,16) owns columns 4c..4c+3.
template <bool FILTER>
__global__ __launch_bounds__(256) void csr_reduce_kernel(
    const uint32_t* __restrict__ row_start, const uint32_t* __restrict__ counts,
    const uint2* __restrict__ pairs, const float* __restrict__ xin,
    float* __restrict__ xout, const int* __restrict__ list, const int* __restrict__ nlist) {
  int wave = (blockIdx.x * 256 + threadIdx.x) >> 6;
  int lane = threadIdx.x & 63;
  int nw = (gridDim.x * 256) >> 6;
  int g = lane >> 4;
  int c = lane & 15;
  int nrows = FILTER ? nlist[0] : N_NODES;
  for (int ii = wave; ii < nrows; ii += nw) {
    int i = FILTER ? list[ii] : ii;
    uint32_t cnt = counts[i];
    uint32_t base = row_start[i];
    float ax = 0.f, ay = 0.f, az = 0.f, aw = 0.f;
    for (uint32_t j0 = 0; j0 < cnt; j0 += 64) {
      int nb = (int)min(64u, cnt - j0);
      uint2 p = make_uint2(0u, 0u);
      if (lane < nb) p = pairs[base + j0 + lane];
      int nq = (nb + 3) >> 2;          // quad-iterations (4 edges each)
      int nqp = (nq + 3) & ~3;         // pad to multiple of 4 (invalid edges masked)
      for (int q = 0; q < nqp; q += 4) {
        int e0 = ((q + 0) << 2) | g;
        int e1 = ((q + 1) << 2) | g;
        int e2_ = ((q + 2) << 2) | g;
        int e3_ = ((q + 3) << 2) | g;
        int s0 = __shfl((int)p.x, e0 & 63, 64);
        int s1 = __shfl((int)p.x, e1 & 63, 64);
        int s2 = __shfl((int)p.x, e2_ & 63, 64);
        int s3 = __shfl((int)p.x, e3_ & 63, 64);
        float v0 = __uint_as_float((uint32_t)__shfl((int)p.y, e0 & 63, 64));
        float v1 = __uint_as_float((uint32_t)__shfl((int)p.y, e1 & 63, 64));
        float v2 = __uint_as_float((uint32_t)__shfl((int)p.y, e2_ & 63, 64));
        float v3 = __uint_as_float((uint32_t)__shfl((int)p.y, e3_ & 63, 64));
        s0 = (e0 < nb) ? s0 : 0;  v0 = (e0 < nb) ? v0 : 0.f;
        s1 = (e1 < nb) ? s1 : 0;  v1 = (e1 < nb) ? v1 : 0.f;
        s2 = (e2_ < nb) ? s2 : 0; v2 = (e2_ < nb) ? v2 : 0.f;
        s3 = (e3_ < nb) ? s3 : 0; v3 = (e3_ < nb) ? v3 : 0.f;
        float4 x0 = ((const float4*)(xin + (size_t)s0 * D))[c];
        float4 x1 = ((const float4*)(xin + (size_t)s1 * D))[c];
        float4 x2 = ((const float4*)(xin + (size_t)s2 * D))[c];
        float4 x3 = ((const float4*)(xin + (size_t)s3 * D))[c];
        ax = fmaf(v0, x0.x, ax); ay = fmaf(v0, x0.y, ay); az = fmaf(v0, x0.z, az); aw = fmaf(v0, x0.w, aw);
        ax = fmaf(v1, x1.x, ax); ay = fmaf(v1, x1.y, ay); az = fmaf(v1, x1.z, az); aw = fmaf(v1, x1.w, aw);
        ax = fmaf(v2, x2.x, ax); ay = fmaf(v2, x2.y, ay); az = fmaf(v2, x2.z, az); aw = fmaf(v2, x2.w, aw);
        ax = fmaf(v3, x3.x, ax); ay = fmaf(v3, x3.y, ay); az = fmaf(v3, x3.z, az); aw = fmaf(v3, x3.w, aw);
      }
    }
    // fold the 4 edge groups: lanes {c, c+16, c+32, c+48} hold partials of same columns
#pragma unroll
    for (int o = 16; o <= 32; o <<= 1) {
      ax += __shfl_xor(ax, o, 64);
      ay += __shfl_xor(ay, o, 64);
      az += __shfl_xor(az, o, 64);
      aw += __shfl_xor(aw, o, 64);
    }
    if (g == 0) {
      ((float4*)(xout + (size_t)i * D))[c] = make_float4(ax, ay, az, aw);
    }
  }
}

// ---------------------------------------------------------------- final: fused acc/l2norm/mix + seq attention
__global__ __launch_bounds__(256) void final_kernel(
    const int* __restrict__ input,
    const float* __restrict__ e20, const float* __restrict__ e21, const float* __restrict__ e22,
    const float* __restrict__ e30, const float* __restrict__ e31, const float* __restrict__ e32,
    const float* __restrict__ att, const float* __restrict__ att_m,
    float* __restrict__ out_Lcas, float* __restrict__ out_cas) {
  __shared__ float cas[LL * D];  // 51.2 KB
  __shared__ float sv[D];
  __shared__ float sscore[LL];
  __shared__ float red[8];
  int b = blockIdx.x, tid = threadIdx.x;
  // v = att_m @ att^T
  if (tid < D) {
    float a = 0.f;
#pragma unroll
    for (int j = 0; j < D; ++j) a = fmaf(att_m[tid * D + j], att[j], a);
    sv[tid] = a;
  }
  __syncthreads();
  int wv = tid >> 6, lane = tid & 63;
  float svl = sv[lane];
  for (int l = wv; l < LL; l += 4) {
    int i = input[b * LL + l];
    size_t o = (size_t)i * D + lane;
    float v20 = e20[o], v21 = e21[o], v22 = e22[o];
    float v30 = e30[o], v31 = e31[o], v32 = e32[o];
    float n21 = fmaxf(sqrtf(wave_sum(v21 * v21)), 1e-12f);
    float n22 = fmaxf(sqrtf(wave_sum(v22 * v22)), 1e-12f);
    float n31 = fmaxf(sqrtf(wave_sum(v31 * v31)), 1e-12f);
    float n32 = fmaxf(sqrtf(wave_sum(v32 * v32)), 1e-12f);
    float a2 = v20 + v21 / n21 + v22 / n22;
    float a3 = v30 + v31 / n31 + v32 / n32;
    float w2 = wave_sum(a2 * svl);
    float w3 = wave_sum(a3 * svl);
    float mx = fmaxf(w2, w3);
    float ex2 = expf(w2 - mx), ex3 = expf(w3 - mx);
    float inv = 1.f / (ex2 + ex3);
    float mix = (ex2 * a2 + ex3 * a3) * inv;
    cas[l * D + lane] = mix;
    out_cas[(size_t)(b * LL + l) * D + lane] = mix;
  }
  __syncthreads();
  // scores vs row 0
  for (int l = wv; l < LL; l += 4) {
    float s = wave_sum(cas[lane] * cas[l * D + lane]) * 0.125f;  // 1/sqrt(64)
    int iv = input[b * LL + l];
    s = (iv == 0) ? -1e9f : s;
    if (lane == 0) sscore[l] = s;
  }
  __syncthreads();
  // softmax over L
  float m = -INFINITY;
  for (int l = tid; l < LL; l += 256) m = fmaxf(m, sscore[l]);
#pragma unroll
  for (int o = 32; o; o >>= 1) m = fmaxf(m, __shfl_xor(m, o, 64));
  if (lane == 0) red[wv] = m;
  __syncthreads();
  m = fmaxf(fmaxf(red[0], red[1]), fmaxf(red[2], red[3]));
  float sum = 0.f;
  for (int l = tid; l < LL; l += 256) sum += expf(sscore[l] - m);
  sum = wave_sum(sum);
  if (lane == 0) red[4 + wv] = sum;
  __syncthreads();
  float inv = 1.f / (red[4] + red[5] + red[6] + red[7]);
  for (int l = tid; l < LL; l += 256) sscore[l] = expf(sscore[l] - m) * inv;
  __syncthreads();
  for (int t = tid; t < LL * D; t += 256)
    out_Lcas[(size_t)b * LL * D + t] = sscore[t >> 6] * cas[t];
}

// ---------------------------------------------------------------- launch
extern "C" void kernel_launch(void* const* d_in, const int* in_sizes, int n_in,
                              void* d_out, int out_size, void* d_ws, size_t ws_size,
                              hipStream_t stream) {
  const int* input = (const int*)d_in[0];
  const int* h_item_idx = (const int*)d_in[1];
  const float* h_item_val = (const float*)d_in[2];
  const int* h_user_idx = (const int*)d_in[3];
  const float* h_user_val = (const float*)d_in[4];
  const float* user_emb = (const float*)d_in[5];
  const float* w0 = (const float*)d_in[6];
  const float* w1 = (const float*)d_in[7];
  const float* b0 = (const float*)d_in[8];
  const float* b1 = (const float*)d_in[9];
  const float* att = (const float*)d_in[10];
  const float* att_m = (const float*)d_in[11];

  float* out = (float*)d_out;
  float* out_Lcas = out;                       // B*L*D
  float* out_cas = out + (size_t)BB * LL * D;  // B*L*D

  const size_t ND = (size_t)N_NODES * D;  // 6.4M floats
  char* ws = (char*)d_ws;
  float* e20 = (float*)ws; ws += ND * 4;
  float* e30 = (float*)ws; ws += ND * 4;
  float* e21 = (float*)ws; ws += ND * 4;
  float* e31 = (float*)ws; ws += ND * 4;
  float* e22 = (float*)ws; ws += ND * 4;
  float* e32 = (float*)ws; ws += ND * 4;
  uint2* pairs = (uint2*)ws; ws += (size_t)NNZ * 8;
  uint32_t* counts = (uint32_t*)ws; ws += (size_t)N_NODES * 4;
  uint32_t* row_start = (uint32_t*)ws; ws += (size_t)N_NODES * 4;
  uint32_t* cursor = (uint32_t*)ws; ws += (size_t)N_NODES * 4;
  uint32_t* bitmap = (uint32_t*)ws; ws += (size_t)BM_WORDS * 4;
  uint32_t* partial = (uint32_t*)ws; ws += 512 * 4;
  int* list = (int*)ws; ws += (size_t)(BB * LL) * 4;
  int* nlist = (int*)ws; ws += 64;

  const int* item_dst = h_item_idx;
  const int* item_src = h_item_idx + NNZ;
  const int* user_dst = h_user_idx;
  const int* user_src = h_user_idx + NNZ;

  // bitmap + compact list of rows actually needed by the output gather
  hipMemsetAsync(bitmap, 0, (size_t)BM_WORDS * 4, stream);
  hipMemsetAsync(nlist, 0, 64, stream);
  mark_kernel<<<(BB * LL + 255) / 256, 256, 0, stream>>>(input, bitmap, list, nlist);

  // gate
  gate_kernel<<<2048, 256, 0, stream>>>(user_emb, w0, w1, b0, b1, e20, e30);

  // ---- item graph: sort once, reduce layer1 (full) + layer2 (filtered)
  hipMemsetAsync(counts, 0, (size_t)N_NODES * 4, stream);
  hist_kernel<<<2048, 256, 0, stream>>>(item_dst, counts);
  scan_phase1<<<NP, 256, 0, stream>>>(counts, partial);
  scan_phase2<<<1, 256, 0, stream>>>(partial, NP);
  scan_phase3<<<NP, 256, 0, stream>>>(counts, partial, row_start, cursor);
  scatter_kernel<<<2048, 256, 0, stream>>>(item_dst, item_src, h_item_val, cursor, pairs);
  csr_reduce_kernel<false><<<4096, 256, 0, stream>>>(row_start, counts, pairs, e20, e21, nullptr, nullptr);
  csr_reduce_kernel<true><<<1024, 256, 0, stream>>>(row_start, counts, pairs, e21, e22, list, nlist);

  // ---- user graph
  hipMemsetAsync(counts, 0, (size_t)N_NODES * 4, stream);
  hist_kernel<<<2048, 256, 0, stream>>>(user_dst, counts);
  scan_phase1<<<NP, 256, 0, stream>>>(counts, partial);
  scan_phase2<<<1, 256, 0, stream>>>(partial, NP);
  scan_phase3<<<NP, 256, 0, stream>>>(counts, partial, row_start, cursor);
  scatter_kernel<<<2048, 256, 0, stream>>>(user_dst, user_src, h_user_val, cursor, pairs);
  csr_reduce_kernel<false><<<4096, 256, 0, stream>>>(row_start, counts, pairs, e30, e31, nullptr, nullptr);
  csr_reduce_kernel<true><<<1024, 256, 0, stream>>>(row_start, counts, pairs, e31, e32, list, nlist);

  // ---- fused acc / l2norm / attention-mix / sequence attention
  final_kernel<<<BB, 256, 0, stream>>>(input, e20, e21, e22, e30, e31, e32,
                                       att, att_m, out_Lcas, out_cas);
}